// Round 1
// baseline (643.430 us; speedup 1.0000x reference)
//
#include <hip/hip_runtime.h>
#include <hip/hip_bf16.h>
#include <math.h>

typedef __bf16 bf16;
typedef __bf16 bf16x8 __attribute__((ext_vector_type(8)));
typedef __bf16 bf16x4 __attribute__((ext_vector_type(4)));
typedef float f32x4 __attribute__((ext_vector_type(4)));

#define NTOK 65536
#define DMODEL 256

// window-order token m -> global token g (the _reverse mapping)
__device__ __forceinline__ int unwin_idx(int m) {
    int widx = m >> 6, t = m & 63;
    int b = widx >> 6, wl = widx & 63;
    return (b << 12) | (((wl >> 3) * 8 + (t >> 3)) << 6) | ((wl & 7) * 8 + (t & 7));
}

// C[M,N] = act(A[M,K] @ W[N,K]^T + bias)
// AMODE 0: A = bf16 plain [M][K]
// AMODE 1: A = windowed fp32 feat + pe (partition fused), K must be 256
// OMODE 0: plain bf16 [M][N]
// OMODE 1: per-window transposed  C[widx][n][t]   (for V)
// OMODE 2: un-windowed bf16 [g][N]
// ACT   1: exact gelu
template<int AMODE, int OMODE, int ACT>
__global__ __launch_bounds__(256, 2)
void gemm_bt(const float* __restrict__ Afp, const float* __restrict__ pe,
             const bf16* __restrict__ Abf,
             const bf16* __restrict__ Wt, const float* __restrict__ bias,
             bf16* __restrict__ C, int N, int K)
{
    __shared__ bf16 As[128][40];   // BK=32 + pad 8 (keeps 16B alignment, breaks bank stride)
    __shared__ bf16 Bs[128][40];
    const int tid = threadIdx.x;
    const int m0 = blockIdx.x * 128, n0 = blockIdx.y * 128;
    const int lane = tid & 63, w = tid >> 6;
    const int wr = w >> 1, wc = w & 1;
    const int lr = lane & 15, lg = lane >> 4;
    const int r = tid >> 1, cs = (tid & 1) * 16;  // staging: row r, 16 elems at cs

    f32x4 acc[4][4];
    const f32x4 zero = {0.f, 0.f, 0.f, 0.f};
#pragma unroll
    for (int mi = 0; mi < 4; ++mi)
#pragma unroll
        for (int nj = 0; nj < 4; ++nj) acc[mi][nj] = zero;

    int gA = 0, tA = 0;
    if (AMODE == 1) {
        int m = m0 + r;
        tA = m & 63;
        gA = unwin_idx(m);
    }

    for (int k0 = 0; k0 < K; k0 += 32) {
        if (AMODE == 0) {
            const bf16* src = Abf + (size_t)(m0 + r) * K + k0 + cs;
            *reinterpret_cast<bf16x8*>(&As[r][cs])     = *reinterpret_cast<const bf16x8*>(src);
            *reinterpret_cast<bf16x8*>(&As[r][cs + 8]) = *reinterpret_cast<const bf16x8*>(src + 8);
        } else {
            const float4* fs = reinterpret_cast<const float4*>(Afp + (size_t)gA * DMODEL + k0 + cs);
            const float4* ps = reinterpret_cast<const float4*>(pe + tA * DMODEL + k0 + cs);
            bf16* dst = &As[r][cs];
#pragma unroll
            for (int q = 0; q < 4; ++q) {
                float4 a = fs[q], p = ps[q];
                dst[q * 4 + 0] = (bf16)(a.x + p.x);
                dst[q * 4 + 1] = (bf16)(a.y + p.y);
                dst[q * 4 + 2] = (bf16)(a.z + p.z);
                dst[q * 4 + 3] = (bf16)(a.w + p.w);
            }
        }
        {
            const bf16* src = Wt + (size_t)(n0 + r) * K + k0 + cs;
            *reinterpret_cast<bf16x8*>(&Bs[r][cs])     = *reinterpret_cast<const bf16x8*>(src);
            *reinterpret_cast<bf16x8*>(&Bs[r][cs + 8]) = *reinterpret_cast<const bf16x8*>(src + 8);
        }
        __syncthreads();
        bf16x8 af[4], bfr[4];
#pragma unroll
        for (int mi = 0; mi < 4; ++mi)
            af[mi] = *reinterpret_cast<const bf16x8*>(&As[wr * 64 + mi * 16 + lr][8 * lg]);
#pragma unroll
        for (int nj = 0; nj < 4; ++nj)
            bfr[nj] = *reinterpret_cast<const bf16x8*>(&Bs[wc * 64 + nj * 16 + lr][8 * lg]);
#pragma unroll
        for (int mi = 0; mi < 4; ++mi)
#pragma unroll
            for (int nj = 0; nj < 4; ++nj)
                acc[mi][nj] = __builtin_amdgcn_mfma_f32_16x16x32_bf16(af[mi], bfr[nj], acc[mi][nj], 0, 0, 0);
        __syncthreads();
    }

#pragma unroll
    for (int mi = 0; mi < 4; ++mi) {
#pragma unroll
        for (int nj = 0; nj < 4; ++nj) {
            int col = n0 + wc * 64 + nj * 16 + lr;
            float bv = bias[col];
#pragma unroll
            for (int i = 0; i < 4; ++i) {
                int row = m0 + wr * 64 + mi * 16 + lg * 4 + i;
                float v = acc[mi][nj][i] + bv;
                if (ACT == 1) v = 0.5f * v * (1.0f + erff(v * 0.70710678118654752f));
                bf16 o = (bf16)v;
                if (OMODE == 0) {
                    C[(size_t)row * N + col] = o;
                } else if (OMODE == 1) {
                    int widx = row >> 6, tt = row & 63;
                    C[((size_t)widx * N + col) * 64 + tt] = o;
                } else {
                    C[(size_t)unwin_idx(row) * N + col] = o;
                }
            }
        }
    }
}

// one wave per (window, head); obuf may alias qbuf (Q fully staged to LDS first,
// each block writes only its own head's column slice)
__global__ __launch_bounds__(64)
void attn_win(const bf16* qbuf, const bf16* __restrict__ kbuf,
              const bf16* __restrict__ vtbuf, bf16* obuf)
{
    __shared__ bf16 Qs[64][72];  // reused for P after S-phase
    __shared__ bf16 Ks[64][72];
    __shared__ bf16 Vs[64][72];  // Vt: row=d_local, col=key
    const int lane = threadIdx.x;
    const int widx = blockIdx.x >> 2, head = blockIdx.x & 3;
    const int lr = lane & 15, lg = lane >> 4;
    const int rr = lane >> 3, jj = lane & 7;

#pragma unroll
    for (int i = 0; i < 8; ++i) {
        int row = i * 8 + rr;
        *reinterpret_cast<bf16x8*>(&Qs[row][jj * 8]) =
            *reinterpret_cast<const bf16x8*>(qbuf + ((size_t)widx * 64 + row) * 256 + head * 64 + jj * 8);
        *reinterpret_cast<bf16x8*>(&Ks[row][jj * 8]) =
            *reinterpret_cast<const bf16x8*>(kbuf + ((size_t)widx * 64 + row) * 256 + head * 64 + jj * 8);
        *reinterpret_cast<bf16x8*>(&Vs[row][jj * 8]) =
            *reinterpret_cast<const bf16x8*>(vtbuf + (size_t)widx * 16384 + (head * 64 + row) * 64 + jj * 8);
    }
    __syncthreads();

    const f32x4 zero = {0.f, 0.f, 0.f, 0.f};
    f32x4 sacc[4][4];
#pragma unroll
    for (int mi = 0; mi < 4; ++mi)
#pragma unroll
        for (int nj = 0; nj < 4; ++nj) sacc[mi][nj] = zero;

#pragma unroll
    for (int k0 = 0; k0 < 64; k0 += 32) {
        bf16x8 af[4], bfr[4];
#pragma unroll
        for (int mi = 0; mi < 4; ++mi)
            af[mi] = *reinterpret_cast<const bf16x8*>(&Qs[mi * 16 + lr][k0 + 8 * lg]);
#pragma unroll
        for (int nj = 0; nj < 4; ++nj)
            bfr[nj] = *reinterpret_cast<const bf16x8*>(&Ks[nj * 16 + lr][k0 + 8 * lg]);
#pragma unroll
        for (int mi = 0; mi < 4; ++mi)
#pragma unroll
            for (int nj = 0; nj < 4; ++nj)
                sacc[mi][nj] = __builtin_amdgcn_mfma_f32_16x16x32_bf16(af[mi], bfr[nj], sacc[mi][nj], 0, 0, 0);
    }

    // softmax over keys (cols). Lane group (lg) shares rows; xor 1,2,4,8 reduces across cols.
    const float c = 0.125f * 1.4426950408889634f;  // log2(e)/sqrt(dh)
    float rmax[4][4], rsum[4][4];
#pragma unroll
    for (int mi = 0; mi < 4; ++mi)
#pragma unroll
        for (int i = 0; i < 4; ++i) {
            float m = fmaxf(fmaxf(sacc[mi][0][i], sacc[mi][1][i]), fmaxf(sacc[mi][2][i], sacc[mi][3][i]));
            m = fmaxf(m, __shfl_xor(m, 1));
            m = fmaxf(m, __shfl_xor(m, 2));
            m = fmaxf(m, __shfl_xor(m, 4));
            m = fmaxf(m, __shfl_xor(m, 8));
            rmax[mi][i] = m;
        }
#pragma unroll
    for (int mi = 0; mi < 4; ++mi)
#pragma unroll
        for (int nj = 0; nj < 4; ++nj)
#pragma unroll
            for (int i = 0; i < 4; ++i)
                sacc[mi][nj][i] = exp2f((sacc[mi][nj][i] - rmax[mi][i]) * c);
#pragma unroll
    for (int mi = 0; mi < 4; ++mi)
#pragma unroll
        for (int i = 0; i < 4; ++i) {
            float s = sacc[mi][0][i] + sacc[mi][1][i] + sacc[mi][2][i] + sacc[mi][3][i];
            s += __shfl_xor(s, 1);
            s += __shfl_xor(s, 2);
            s += __shfl_xor(s, 4);
            s += __shfl_xor(s, 8);
            rsum[mi][i] = s;
        }
    __syncthreads();  // Qs reads done; reuse as P
#pragma unroll
    for (int mi = 0; mi < 4; ++mi)
#pragma unroll
        for (int nj = 0; nj < 4; ++nj)
#pragma unroll
            for (int i = 0; i < 4; ++i)
                Qs[mi * 16 + lg * 4 + i][nj * 16 + lr] = (bf16)sacc[mi][nj][i];
    __syncthreads();

    f32x4 oacc[4][4];
#pragma unroll
    for (int mi = 0; mi < 4; ++mi)
#pragma unroll
        for (int nj = 0; nj < 4; ++nj) oacc[mi][nj] = zero;
#pragma unroll
    for (int k0 = 0; k0 < 64; k0 += 32) {
        bf16x8 af[4], bfr[4];
#pragma unroll
        for (int mi = 0; mi < 4; ++mi)
            af[mi] = *reinterpret_cast<const bf16x8*>(&Qs[mi * 16 + lr][k0 + 8 * lg]);
#pragma unroll
        for (int nj = 0; nj < 4; ++nj)
            bfr[nj] = *reinterpret_cast<const bf16x8*>(&Vs[nj * 16 + lr][k0 + 8 * lg]);
#pragma unroll
        for (int mi = 0; mi < 4; ++mi)
#pragma unroll
            for (int nj = 0; nj < 4; ++nj)
                oacc[mi][nj] = __builtin_amdgcn_mfma_f32_16x16x32_bf16(af[mi], bfr[nj], oacc[mi][nj], 0, 0, 0);
    }
#pragma unroll
    for (int mi = 0; mi < 4; ++mi)
#pragma unroll
        for (int i = 0; i < 4; ++i) {
            float inv = 1.0f / rsum[mi][i];
            int row = mi * 16 + lg * 4 + i;
#pragma unroll
            for (int nj = 0; nj < 4; ++nj) {
                int col = nj * 16 + lr;
                obuf[((size_t)widx * 64 + row) * 256 + head * 64 + col] = (bf16)(oacc[mi][nj][i] * inv);
            }
        }
}

// y = LN(resf + xbf) * gamma + beta ; writes fp32 and/or bf16
__global__ __launch_bounds__(256)
void ln_fuse(const bf16* __restrict__ xbf, const float* __restrict__ resf,
             const float* __restrict__ gamma, const float* __restrict__ beta,
             float* __restrict__ outf, bf16* __restrict__ outb)
{
    int row = blockIdx.x * 4 + (threadIdx.x >> 6);
    int lane = threadIdx.x & 63;
    size_t base = (size_t)row * 256 + lane * 4;
    float4 rv = *reinterpret_cast<const float4*>(resf + base);
    bf16x4 xv = *reinterpret_cast<const bf16x4*>(xbf + base);
    float v[4];
    v[0] = rv.x + (float)xv[0];
    v[1] = rv.y + (float)xv[1];
    v[2] = rv.z + (float)xv[2];
    v[3] = rv.w + (float)xv[3];
    float s = v[0] + v[1] + v[2] + v[3];
    float q = v[0] * v[0] + v[1] * v[1] + v[2] * v[2] + v[3] * v[3];
#pragma unroll
    for (int m = 1; m < 64; m <<= 1) {
        s += __shfl_xor(s, m);
        q += __shfl_xor(q, m);
    }
    float mean = s * (1.f / 256.f);
    float var = q * (1.f / 256.f) - mean * mean;
    float rstd = rsqrtf(var + 1e-5f);
    float4 gv = *reinterpret_cast<const float4*>(gamma + lane * 4);
    float4 bv = *reinterpret_cast<const float4*>(beta + lane * 4);
    float o[4];
    o[0] = (v[0] - mean) * rstd * gv.x + bv.x;
    o[1] = (v[1] - mean) * rstd * gv.y + bv.y;
    o[2] = (v[2] - mean) * rstd * gv.z + bv.z;
    o[3] = (v[3] - mean) * rstd * gv.w + bv.w;
    if (outf) {
        float4 ov;
        ov.x = o[0]; ov.y = o[1]; ov.z = o[2]; ov.w = o[3];
        *reinterpret_cast<float4*>(outf + base) = ov;
    }
    if (outb) {
        bf16x4 ob;
        ob[0] = (bf16)o[0]; ob[1] = (bf16)o[1]; ob[2] = (bf16)o[2]; ob[3] = (bf16)o[3];
        *reinterpret_cast<bf16x4*>(outb + base) = ob;
    }
}

__global__ void cvt_bf16(const float* __restrict__ s, bf16* __restrict__ d, int n)
{
    int i = blockIdx.x * 256 + threadIdx.x;
    if (i < n) d[i] = (bf16)s[i];
}

extern "C" void kernel_launch(void* const* d_in, const int* in_sizes, int n_in,
                              void* d_out, int out_size, void* d_ws, size_t ws_size,
                              hipStream_t stream)
{
    const float* feat_A       = (const float*)d_in[0];
    const float* feat_B       = (const float*)d_in[1];
    const float* pe           = (const float*)d_in[2];
    const float* qkv_w_A      = (const float*)d_in[3];
    const float* qkv_b_A      = (const float*)d_in[4];
    const float* out_w_A      = (const float*)d_in[5];
    const float* out_b_A      = (const float*)d_in[6];
    const float* norm_g_A     = (const float*)d_in[7];
    const float* norm_b_A     = (const float*)d_in[8];
    const float* ffn_norm_g_A = (const float*)d_in[9];
    const float* ffn_norm_b_A = (const float*)d_in[10];
    const float* ffn_w1_A     = (const float*)d_in[11];
    const float* ffn_b1_A     = (const float*)d_in[12];
    const float* ffn_w2_A     = (const float*)d_in[13];
    const float* ffn_b2_A     = (const float*)d_in[14];
    const float* qkv_w_B      = (const float*)d_in[15];
    const float* qkv_b_B      = (const float*)d_in[16];
    const float* out_w_B      = (const float*)d_in[17];
    const float* out_b_B      = (const float*)d_in[18];
    const float* norm_g_B     = (const float*)d_in[19];
    const float* norm_b_B     = (const float*)d_in[20];
    const float* ffn_norm_g_B = (const float*)d_in[21];
    const float* ffn_norm_b_B = (const float*)d_in[22];
    const float* ffn_w1_B     = (const float*)d_in[23];
    const float* ffn_b1_B     = (const float*)d_in[24];
    const float* ffn_w2_B     = (const float*)d_in[25];
    const float* ffn_b2_B     = (const float*)d_in[26];

    char* ws = (char*)d_ws;
    const size_t BFE = (size_t)NTOK * DMODEL;      // 16,777,216 elems
    const size_t BFB = BFE * 2;                    // bytes per bf16 activation buffer

    bf16* Wb = (bf16*)ws;                          // 1,048,576 bf16 = 2 MB
    size_t off = 2u * 1024 * 1024;
    bf16* qA = (bf16*)(ws + off); off += BFB;
    bf16* kA = (bf16*)(ws + off); off += BFB;
    bf16* vA = (bf16*)(ws + off); off += BFB;
    bf16* qB = (bf16*)(ws + off); off += BFB;
    bf16* kB = (bf16*)(ws + off); off += BFB;
    bf16* vB = (bf16*)(ws + off); off += BFB;
    bf16* hb = (bf16*)(ws + off); off += BFB * 2;  // 65536 x 512
    bf16* tb = (bf16*)(ws + off); off += BFB;
    // region reuse after attention+proj consume q/k/v:
    float* y1A   = (float*)kA;   // spans kA+vA (67 MB)
    float* y1B   = (float*)kB;   // spans kB+vB
    bf16*  y1Abf = qA;
    bf16*  y1Bbf = qB;

    bf16* w_qkvA = Wb + 0;
    bf16* w_outA = Wb + 196608;
    bf16* w_f1A  = Wb + 262144;
    bf16* w_f2A  = Wb + 393216;
    bf16* w_qkvB = Wb + 524288;
    bf16* w_outB = Wb + 720896;
    bf16* w_f1B  = Wb + 786432;
    bf16* w_f2B  = Wb + 917504;

    cvt_bf16<<<(196608 + 255) / 256, 256, 0, stream>>>(qkv_w_A, w_qkvA, 196608);
    cvt_bf16<<<(65536 + 255) / 256, 256, 0, stream>>>(out_w_A, w_outA, 65536);
    cvt_bf16<<<(131072 + 255) / 256, 256, 0, stream>>>(ffn_w1_A, w_f1A, 131072);
    cvt_bf16<<<(131072 + 255) / 256, 256, 0, stream>>>(ffn_w2_A, w_f2A, 131072);
    cvt_bf16<<<(196608 + 255) / 256, 256, 0, stream>>>(qkv_w_B, w_qkvB, 196608);
    cvt_bf16<<<(65536 + 255) / 256, 256, 0, stream>>>(out_w_B, w_outB, 65536);
    cvt_bf16<<<(131072 + 255) / 256, 256, 0, stream>>>(ffn_w1_B, w_f1B, 131072);
    cvt_bf16<<<(131072 + 255) / 256, 256, 0, stream>>>(ffn_w2_B, w_f2B, 131072);

    dim3 blk(256);
    dim3 g256(512, 2), g512(512, 4);

    // QKV projections (window partition + PE fused into A staging)
    gemm_bt<1, 0, 0><<<g256, blk, 0, stream>>>(feat_A, pe, nullptr, w_qkvA,          qkv_b_A,       qA, 256, 256);
    gemm_bt<1, 0, 0><<<g256, blk, 0, stream>>>(feat_B, pe, nullptr, w_qkvA + 65536,  qkv_b_A + 256, kA, 256, 256);
    gemm_bt<1, 1, 0><<<g256, blk, 0, stream>>>(feat_B, pe, nullptr, w_qkvA + 131072, qkv_b_A + 512, vA, 256, 256);
    gemm_bt<1, 0, 0><<<g256, blk, 0, stream>>>(feat_B, pe, nullptr, w_qkvB,          qkv_b_B,       qB, 256, 256);
    gemm_bt<1, 0, 0><<<g256, blk, 0, stream>>>(feat_A, pe, nullptr, w_qkvB + 65536,  qkv_b_B + 256, kB, 256, 256);
    gemm_bt<1, 1, 0><<<g256, blk, 0, stream>>>(feat_A, pe, nullptr, w_qkvB + 131072, qkv_b_B + 512, vB, 256, 256);

    attn_win<<<4096, 64, 0, stream>>>(qA, kA, vA, qA);
    attn_win<<<4096, 64, 0, stream>>>(qB, kB, vB, qB);

    // out-proj (un-window in epilogue) + residual LN
    gemm_bt<0, 2, 0><<<g256, blk, 0, stream>>>(nullptr, nullptr, qA, w_outA, out_b_A, tb, 256, 256);
    ln_fuse<<<16384, 256, 0, stream>>>(tb, feat_A, norm_g_A, norm_b_A, y1A, y1Abf);
    gemm_bt<0, 2, 0><<<g256, blk, 0, stream>>>(nullptr, nullptr, qB, w_outB, out_b_B, tb, 256, 256);
    ln_fuse<<<16384, 256, 0, stream>>>(tb, feat_B, norm_g_B, norm_b_B, y1B, y1Bbf);

    // FFN + LN, stream A then B (share hb/tb scratch)
    gemm_bt<0, 0, 1><<<g512, blk, 0, stream>>>(nullptr, nullptr, y1Abf, w_f1A, ffn_b1_A, hb, 512, 256);
    gemm_bt<0, 0, 0><<<g256, blk, 0, stream>>>(nullptr, nullptr, hb,    w_f2A, ffn_b2_A, tb, 256, 512);
    ln_fuse<<<16384, 256, 0, stream>>>(tb, y1A, ffn_norm_g_A, ffn_norm_b_A, (float*)d_out, nullptr);

    gemm_bt<0, 0, 1><<<g512, blk, 0, stream>>>(nullptr, nullptr, y1Bbf, w_f1B, ffn_b1_B, hb, 512, 256);
    gemm_bt<0, 0, 0><<<g256, blk, 0, stream>>>(nullptr, nullptr, hb,    w_f2B, ffn_b2_B, tb, 256, 512);
    ln_fuse<<<16384, 256, 0, stream>>>(tb, y1B, ffn_norm_g_B, ffn_norm_b_B, (float*)d_out + BFE, nullptr);
}